// Round 5
// baseline (670.086 us; speedup 1.0000x reference)
//
#include <hip/hip_runtime.h>

// ---------------------------------------------------------------------------
// GraphSAGE 2-layer hetero (R=2) + edge dot scorer.  Round 5:
//  * CSR build = 2-pass radix by dst bucket (128 nodes/bucket): LDS-staged
//    partition into (src,dst) pair staging (aliases acc), then one block per
//    bucket -> node offsets + csr in a contiguous region. No scattered-4B
//    global writes, no serial scan.
//  * Gathered tables stored column-SLICED (8 slices): slice s contiguous
//    [s][N][16] (feat) / [s][N][8] (h2) => per-slice table 1.6/0.8 MB fits a
//    single XCD L2; blockIdx%8 pins slice->XCD (perf heuristic).
//  * gather_mean: lane = node (no cross-lane reduce); score: per-slice
//    partial dots (partials alias acc) + reduce kernel.
// ---------------------------------------------------------------------------

#define BW 128            // nodes per radix bucket (pow2)
#define NBK_MAX 1024      // max buckets per relation (N <= 131072)

__device__ __forceinline__ unsigned short f2bf(float f) {
    unsigned u = __float_as_uint(f);
    unsigned r = u + 0x7FFFu + ((u >> 16) & 1u);
    return (unsigned short)(r >> 16);
}
__device__ __forceinline__ unsigned pack2(float a, float b) {
    return (unsigned)f2bf(a) | ((unsigned)f2bf(b) << 16);
}
__device__ __forceinline__ float bflo(unsigned v) { return __uint_as_float(v << 16); }
__device__ __forceinline__ float bfhi(unsigned v) { return __uint_as_float(v & 0xFFFF0000u); }

// ---- radix pass A: per-(r,bucket) counts --------------------------------
__global__ __launch_bounds__(256) void
bucket_count_kernel(const int* __restrict__ edges, int* __restrict__ bcnt,
                    int NBK, int E)
{
    __shared__ int cnt[2 * NBK_MAX];
    const int rbT = 2 * NBK;
    const int t = threadIdx.x;
    for (int k = t; k < rbT; k += 256) cnt[k] = 0;
    __syncthreads();
    long long start = (long long)blockIdx.x * 4096;
    long long twoE = 2LL * E;
#pragma unroll
    for (int u = 0; u < 16; ++u) {
        long long idx = start + u * 256 + t;
        if (idx < twoE) {
            int r = idx >= E;
            int e = (int)(idx - (long long)r * E);
            int d = edges[(size_t)r * 2 * E + E + e];
            atomicAdd(&cnt[r * NBK + (d >> 7)], 1);
        }
    }
    __syncthreads();
    for (int k = t; k < rbT; k += 256)
        if (cnt[k]) atomicAdd(&bcnt[k], cnt[k]);
}

// ---- radix pass B: exclusive scan of bucket counts (one block) ----------
__global__ __launch_bounds__(1024) void
bucket_scan_kernel(const int* __restrict__ bcnt, int* __restrict__ bko,
                   int rbT, int twoE)
{
    __shared__ int sm[1024];
    int t = threadIdx.x;
    int v = (t < rbT) ? bcnt[t] : 0;
    sm[t] = v;
    __syncthreads();
    for (int s = 1; s < 1024; s <<= 1) {
        int u = (t >= s) ? sm[t - s] : 0;
        __syncthreads();
        sm[t] += u;
        __syncthreads();
    }
    if (t < rbT) bko[t] = sm[t] - v;
    if (t == 0) bko[rbT] = twoE;
}

// ---- radix pass C: partition edges into bucket-grouped (src,dst) pairs --
__global__ __launch_bounds__(256) void
partition_kernel(const int* __restrict__ edges, const int* __restrict__ bko,
                 int* __restrict__ gcur, uint2* __restrict__ staging,
                 int NBK, int E)
{
    __shared__ int cnt[2 * NBK_MAX];
    __shared__ int base[2 * NBK_MAX];
    const int rbT = 2 * NBK;
    const int t = threadIdx.x;
    for (int k = t; k < rbT; k += 256) cnt[k] = 0;
    __syncthreads();
    long long start = (long long)blockIdx.x * 4096;
    long long twoE = 2LL * E;
    int srcs[16], dsts[16], rbs[16];
#pragma unroll
    for (int u = 0; u < 16; ++u) {
        long long idx = start + u * 256 + t;
        rbs[u] = -1;
        if (idx < twoE) {
            int r = idx >= E;
            int e = (int)(idx - (long long)r * E);
            srcs[u] = edges[(size_t)r * 2 * E + e];
            int d = edges[(size_t)r * 2 * E + E + e];
            dsts[u] = d;
            rbs[u] = r * NBK + (d >> 7);
            atomicAdd(&cnt[rbs[u]], 1);
        }
    }
    __syncthreads();
    for (int k = t; k < rbT; k += 256) {
        int c0 = cnt[k];
        if (c0) base[k] = bko[k] + atomicAdd(&gcur[k], c0);
        cnt[k] = 0;
    }
    __syncthreads();
#pragma unroll
    for (int u = 0; u < 16; ++u) {
        if (rbs[u] >= 0) {
            int pos = atomicAdd(&cnt[rbs[u]], 1);
            staging[(size_t)base[rbs[u]] + pos] = make_uint2((unsigned)srcs[u], (unsigned)dsts[u]);
        }
    }
}

// ---- radix pass D: per-bucket node hist/scan -> off[] and csr[] ----------
__global__ __launch_bounds__(256) void
bucket_csr_kernel(const uint2* __restrict__ staging, const int* __restrict__ bko,
                  int* __restrict__ csr, int* __restrict__ off,
                  int NBK, int N)
{
    __shared__ int hist[BW], excl[BW], cur[BW], sc[BW];
    const int rb = blockIdx.x;
    const int r = rb / NBK;
    const int b = rb % NBK;
    const int node0 = b * BW;
    const int nn = min(BW, N - node0);
    const int cbase = bko[rb];
    const int c = bko[rb + 1] - cbase;
    const int t = threadIdx.x;

    if (t < BW) { hist[t] = 0; cur[t] = 0; }
    __syncthreads();
    for (int k = t; k < c; k += 256)
        atomicAdd(&hist[(int)staging[(size_t)cbase + k].y - node0], 1);
    __syncthreads();
    if (t < BW) sc[t] = hist[t];
    __syncthreads();
    for (int s = 1; s < BW; s <<= 1) {
        int v = (t < BW && t >= s) ? sc[t - s] : 0;
        __syncthreads();
        if (t < BW) sc[t] += v;
        __syncthreads();
    }
    if (t < BW) excl[t] = sc[t] - hist[t];
    if (t < nn) off[(size_t)r * N + node0 + t] = cbase + excl[t];
    __syncthreads();
    for (int k = t; k < c; k += 256) {
        uint2 pr = staging[(size_t)cbase + k];
        int l = (int)pr.y - node0;
        int pos = atomicAdd(&cur[l], 1);
        csr[(size_t)cbase + excl[l] + pos] = (int)pr.x;
    }
}

// ---- x -> bf16, column-sliced [8][N][16] --------------------------------
__global__ __launch_bounds__(256) void
cvt_sliced_kernel(const float* __restrict__ x, unsigned short* __restrict__ xb, int N)
{
    int t = blockIdx.x * blockDim.x + threadIdx.x;
    if (t >= N * 16) return;
    int n = t >> 4;
    int sub = t & 15;
    int slice = sub >> 1;
    int half = sub & 1;
    const float* ip = x + (size_t)n * 128 + slice * 16 + half * 8;
    float4 v0 = *(const float4*)ip;
    float4 v1 = *(const float4*)(ip + 4);
    uint4 o;
    o.x = pack2(v0.x, v0.y); o.y = pack2(v0.z, v0.w);
    o.z = pack2(v1.x, v1.y); o.w = pack2(v1.z, v1.w);
    *(uint4*)(xb + ((size_t)slice * N + n) * 16 + half * 8) = o;
}

// ---- Wself/bias combine --------------------------------------------------
__global__ void prep_kernel(const float* __restrict__ Ws1, const float* __restrict__ b1,
                            const float* __restrict__ Ws2, const float* __restrict__ b2,
                            float* __restrict__ Wc1, float* __restrict__ bc1,
                            float* __restrict__ Wc2, float* __restrict__ bc2)
{
    int t = blockIdx.x * blockDim.x + threadIdx.x;
    if (t < 16384) Wc1[t] = Ws1[t] + Ws1[16384 + t];
    if (t < 128)   bc1[t] = b1[t] + b1[128 + t];
    if (t < 8192)  Wc2[t] = Ws2[t] + Ws2[8192 + t];
    if (t < 64)    bc2[t] = b2[t] + b2[64 + t];
}

// ---- gather mean: lane = (r,node), slice = blockIdx%8 (XCD-pinned) -------
// featb sliced [8][N][16] bf16; acc [2][N][128] f32; off global into csr[2E].
__global__ __launch_bounds__(256) void
gather_mean_kernel(const unsigned short* __restrict__ featb,
                   const int* __restrict__ csr, const int* __restrict__ off,
                   float* __restrict__ acc, int N, int twoE)
{
    int slice = blockIdx.x & 7;
    int p = (blockIdx.x >> 3) * 256 + threadIdx.x;
    if (p >= 2 * N) return;
    int o0 = off[p];
    int o1 = (p + 1 < 2 * N) ? off[p + 1] : twoE;
    int d = o1 - o0;
    const unsigned short* tb = featb + (size_t)slice * N * 16;

    float f[16];
#pragma unroll
    for (int c = 0; c < 16; ++c) f[c] = 0.0f;

    for (int j = o0; j < o1; ++j) {
        int s = csr[j];
        uint4 lo = *(const uint4*)(tb + (size_t)s * 16);
        uint4 hi = *(const uint4*)(tb + (size_t)s * 16 + 8);
        f[0] += bflo(lo.x);  f[1] += bfhi(lo.x);
        f[2] += bflo(lo.y);  f[3] += bfhi(lo.y);
        f[4] += bflo(lo.z);  f[5] += bfhi(lo.z);
        f[6] += bflo(lo.w);  f[7] += bfhi(lo.w);
        f[8] += bflo(hi.x);  f[9] += bfhi(hi.x);
        f[10] += bflo(hi.y); f[11] += bfhi(hi.y);
        f[12] += bflo(hi.z); f[13] += bfhi(hi.z);
        f[14] += bflo(hi.w); f[15] += bfhi(hi.w);
    }
    float inv = 1.0f / fmaxf((float)d, 1.0f);
    float* op = acc + (size_t)p * 128 + slice * 16;
#pragma unroll
    for (int q = 0; q < 4; ++q) {
        float4 v;
        v.x = f[q * 4 + 0] * inv; v.y = f[q * 4 + 1] * inv;
        v.z = f[q * 4 + 2] * inv; v.w = f[q * 4 + 3] * inv;
        *(float4*)(op + q * 4) = v;
    }
}

// ---- fused 3-GEMM: out = relu?(A0b@W0 + A1@W1 + A2@W2 + bias) -----------
// A0b bf16 sliced [8][N][16]; A1,A2 f32 [N][128]; W f32 [128][BN].
// Output bf16 sliced: BN=128 -> [8][N][16], BN=64 -> [8][N][8].
template<int BN>
__global__ __launch_bounds__(256) void
gemm3_kernel(const unsigned short* __restrict__ A0b,
             const float* __restrict__ A1, const float* __restrict__ A2,
             const float* __restrict__ W0, const float* __restrict__ W1,
             const float* __restrict__ W2,
             const float* __restrict__ bias,
             unsigned short* __restrict__ outb,
             int N, int do_relu)
{
    constexpr int TCOLS = BN / 4;
    constexpr int TROWS = 256 / TCOLS;
    constexpr int BM = TROWS * 8;
    constexpr int BK = 32;
    constexpr int F4_PER_WROW = BN / 4;
    constexpr int OSW = (BN == 128) ? 16 : 8;   // output slice width

    __shared__ float As[BK][BM + 4];
    __shared__ float Wsm[BK][BN];

    const int tid = threadIdx.x;
    const int tc = tid % TCOLS;
    const int tr = tid / TCOLS;
    const int j0 = tc * 4;
    const int i0 = tr * 8;
    const int rowBase = blockIdx.x * BM;

    float acc[8][4];
#pragma unroll
    for (int r = 0; r < 8; ++r)
#pragma unroll
        for (int c = 0; c < 4; ++c) acc[r][c] = 0.0f;

    const float* Wps[3] = {W0, W1, W2};

    for (int s = 0; s < 3; ++s) {
        const float* A = (s == 1) ? A1 : A2;
        const float* W = Wps[s];
        for (int k0 = 0; k0 < 128; k0 += BK) {
            if (s == 0) {
                // bf16 sliced A tile: BM rows x 32 cols; slice width 16.
                constexpr int A_U4 = BM * 4;
#pragma unroll
                for (int p = 0; p < A_U4 / 256; ++p) {
                    int q = tid + p * 256;
                    int row = q >> 2;
                    int part = q & 3;
                    int kq = part * 8;
                    int rg = rowBase + row;
                    if (rg >= N) rg = N - 1;
                    int slice = (k0 >> 4) + (part >> 1);
                    int half = part & 1;
                    uint4 v = *(const uint4*)(A0b + ((size_t)slice * N + rg) * 16 + half * 8);
                    As[kq + 0][row] = bflo(v.x);
                    As[kq + 1][row] = bfhi(v.x);
                    As[kq + 2][row] = bflo(v.y);
                    As[kq + 3][row] = bfhi(v.y);
                    As[kq + 4][row] = bflo(v.z);
                    As[kq + 5][row] = bfhi(v.z);
                    As[kq + 6][row] = bflo(v.w);
                    As[kq + 7][row] = bfhi(v.w);
                }
            } else {
                constexpr int A_F4 = BM * (BK / 4);
#pragma unroll
                for (int p = 0; p < A_F4 / 256; ++p) {
                    int q = tid + p * 256;
                    int row = q >> 3;
                    int kq = (q & 7) * 4;
                    int rg = rowBase + row;
                    if (rg >= N) rg = N - 1;
                    float4 v = *(const float4*)(A + (size_t)rg * 128 + k0 + kq);
                    As[kq + 0][row] = v.x;
                    As[kq + 1][row] = v.y;
                    As[kq + 2][row] = v.z;
                    As[kq + 3][row] = v.w;
                }
            }
            constexpr int W_F4 = BK * F4_PER_WROW;
#pragma unroll
            for (int p = 0; p < W_F4 / 256; ++p) {
                int q = tid + p * 256;
                int rk = q / F4_PER_WROW;
                int jq = (q % F4_PER_WROW) * 4;
                float4 v = *(const float4*)(W + (size_t)(k0 + rk) * BN + jq);
                *(float4*)&Wsm[rk][jq] = v;
            }
            __syncthreads();

#pragma unroll 8
            for (int k = 0; k < BK; ++k) {
                float4 w = *(const float4*)&Wsm[k][j0];
                const float* ap = &As[k][i0];
                float4 a0 = *(const float4*)(ap);
                float4 a1 = *(const float4*)(ap + 4);
                float av[8] = {a0.x, a0.y, a0.z, a0.w, a1.x, a1.y, a1.z, a1.w};
#pragma unroll
                for (int r = 0; r < 8; ++r) {
                    acc[r][0] = fmaf(av[r], w.x, acc[r][0]);
                    acc[r][1] = fmaf(av[r], w.y, acc[r][1]);
                    acc[r][2] = fmaf(av[r], w.z, acc[r][2]);
                    acc[r][3] = fmaf(av[r], w.w, acc[r][3]);
                }
            }
            __syncthreads();
        }
    }

    float4 bv = *(const float4*)(bias + j0);
    const int oslice = j0 / OSW;
    const int ocol = j0 % OSW;
#pragma unroll
    for (int r = 0; r < 8; ++r) {
        int row = rowBase + i0 + r;
        if (row >= N) break;
        float4 o;
        o.x = acc[r][0] + bv.x;
        o.y = acc[r][1] + bv.y;
        o.z = acc[r][2] + bv.z;
        o.w = acc[r][3] + bv.w;
        if (do_relu) {
            o.x = fmaxf(o.x, 0.0f); o.y = fmaxf(o.y, 0.0f);
            o.z = fmaxf(o.z, 0.0f); o.w = fmaxf(o.w, 0.0f);
        }
        ushort4 ob;
        ob.x = f2bf(o.x); ob.y = f2bf(o.y); ob.z = f2bf(o.z); ob.w = f2bf(o.w);
        *(ushort4*)(outb + ((size_t)oslice * N + row) * OSW + ocol) = ob;
    }
}

// ---- score partials: slice = blockIdx%8, h2b sliced [8][N][8] -----------
__global__ __launch_bounds__(256) void
score_part_kernel(const unsigned short* __restrict__ h2b,
                  const int* __restrict__ src, const int* __restrict__ dst,
                  float* __restrict__ part, int E, int N)
{
    int slice = blockIdx.x & 7;
    int e = (blockIdx.x >> 3) * 256 + threadIdx.x;
    if (e >= E) return;
    const unsigned short* tb = h2b + (size_t)slice * N * 8;
    uint4 a = *(const uint4*)(tb + (size_t)src[e] * 8);
    uint4 b = *(const uint4*)(tb + (size_t)dst[e] * 8);
    float s = 0.0f;
    s = fmaf(bflo(a.x), bflo(b.x), s);
    s = fmaf(bfhi(a.x), bfhi(b.x), s);
    s = fmaf(bflo(a.y), bflo(b.y), s);
    s = fmaf(bfhi(a.y), bfhi(b.y), s);
    s = fmaf(bflo(a.z), bflo(b.z), s);
    s = fmaf(bfhi(a.z), bfhi(b.z), s);
    s = fmaf(bflo(a.w), bflo(b.w), s);
    s = fmaf(bfhi(a.w), bfhi(b.w), s);
    part[(size_t)slice * E + e] = s;
}

__global__ __launch_bounds__(256) void
score_reduce_kernel(const float* __restrict__ part_pos,
                    const float* __restrict__ part_neg,
                    float* __restrict__ out, int E, int En)
{
    int t = blockIdx.x * blockDim.x + threadIdx.x;
    if (t >= E + En) return;
    const float* base;
    int e, stride;
    if (t < E) { base = part_pos; e = t; stride = E; }
    else       { base = part_neg; e = t - E; stride = En; }
    float s = 0.0f;
#pragma unroll
    for (int q = 0; q < 8; ++q) s += base[(size_t)q * stride + e];
    out[t] = s;
}

extern "C" void kernel_launch(void* const* d_in, const int* in_sizes, int n_in,
                              void* d_out, int out_size, void* d_ws, size_t ws_size,
                              hipStream_t stream)
{
    const float* x     = (const float*)d_in[0];
    const int*   edges = (const int*)d_in[1];
    const int*   neg   = (const int*)d_in[2];
    const float* Wn1   = (const float*)d_in[3];
    const float* Ws1   = (const float*)d_in[4];
    const float* b1    = (const float*)d_in[5];
    const float* Wn2   = (const float*)d_in[6];
    const float* Ws2   = (const float*)d_in[7];
    const float* b2    = (const float*)d_in[8];
    float* out = (float*)d_out;

    const int Fin = 128, R = 2;
    const int N  = in_sizes[0] / Fin;        // 50000
    const int E  = in_sizes[1] / (R * 2);    // 800000
    const int En = in_sizes[2] / 2;          // 800000
    const int twoE = 2 * E;
    const int NBK = (N + BW - 1) / BW;       // 391
    const int rbT = 2 * NBK;

    float* ws  = (float*)d_ws;
    float* acc = ws;                                   // [2,N,128] f32 (51.2 MB)
                                                       //   aliases: staging pairs, score partials
    float* Wc1 = acc + (size_t)2 * N * 128;            // [128,128]
    float* bc1 = Wc1 + 128 * 128;
    float* Wc2 = bc1 + 128;                            // [128,64]
    float* bc2 = Wc2 + 128 * 64;
    int*   bcnt = (int*)(bc2 + 64);                    // [2*NBK_MAX]
    int*   gcur = bcnt + 2 * NBK_MAX;                  // [2*NBK_MAX]
    int*   bko  = gcur + 2 * NBK_MAX;                  // [2*NBK_MAX+1]
    int*   off  = bko + 2 * NBK_MAX + 1;               // [2N] global csr offsets
    int*   csr  = off + (size_t)2 * N;                 // [2E]
    unsigned short* xb  = (unsigned short*)(csr + (size_t)twoE); // [8][N][16]
    unsigned short* h1b = xb + (size_t)N * 128;        // [8][N][16]
    unsigned short* h2b = h1b + (size_t)N * 128;       // [8][N][8]

    uint2* staging = (uint2*)acc;                      // [2E] pairs (12.8 MB)
    float* part_pos = acc;                             // [8][E]
    float* part_neg = acc + (size_t)8 * E;             // [8][En]

    const int BS = 256;
    const int edge_blocks = (twoE + 4095) / 4096;

    // ---- CSR build (radix by dst bucket) ----
    hipMemsetAsync(bcnt, 0, (size_t)4 * NBK_MAX * sizeof(int), stream);
    bucket_count_kernel<<<edge_blocks, BS, 0, stream>>>(edges, bcnt, NBK, E);
    bucket_scan_kernel<<<1, 1024, 0, stream>>>(bcnt, bko, rbT, twoE);
    partition_kernel<<<edge_blocks, BS, 0, stream>>>(edges, bko, gcur, staging, NBK, E);
    bucket_csr_kernel<<<rbT, BS, 0, stream>>>(staging, bko, csr, off, NBK, N);

    // ---- prep: x -> bf16 sliced, combined weights ----
    cvt_sliced_kernel<<<(N * 16 + BS - 1) / BS, BS, 0, stream>>>(x, xb, N);
    prep_kernel<<<(16384 + BS - 1) / BS, BS, 0, stream>>>(Ws1, b1, Ws2, b2, Wc1, bc1, Wc2, bc2);

    const int gm_blocks = 8 * ((2 * N + BS - 1) / BS);

    // ---- Layer 1 ----
    gather_mean_kernel<<<gm_blocks, BS, 0, stream>>>(xb, csr, off, acc, N, twoE);
    gemm3_kernel<128><<<(N + 63) / 64, BS, 0, stream>>>(
        xb, acc, acc + (size_t)N * 128, Wc1, Wn1, Wn1 + (size_t)128 * 128, bc1, h1b, N, 1);

    // ---- Layer 2 ----
    gather_mean_kernel<<<gm_blocks, BS, 0, stream>>>(h1b, csr, off, acc, N, twoE);
    gemm3_kernel<64><<<(N + 127) / 128, BS, 0, stream>>>(
        h1b, acc, acc + (size_t)N * 128, Wc2, Wn2, Wn2 + (size_t)128 * 64, bc2, h2b, N, 0);

    // ---- Scores (partials alias acc; gemm2 is done with acc) ----
    score_part_kernel<<<8 * ((E + BS - 1) / BS), BS, 0, stream>>>(h2b, edges, edges + E, part_pos, E, N);
    score_part_kernel<<<8 * ((En + BS - 1) / BS), BS, 0, stream>>>(h2b, neg, neg + En, part_neg, En, N);
    score_reduce_kernel<<<(E + En + BS - 1) / BS, BS, 0, stream>>>(part_pos, part_neg, out, E, En);
}

// Round 6
// 452.207 us; speedup vs baseline: 1.4818x; 1.4818x over previous
//
#include <hip/hip_runtime.h>

// ---------------------------------------------------------------------------
// GraphSAGE 2-layer hetero (R=2) + edge dot scorer.  Round 6:
//  * transform-then-aggregate: y_r = x @ Wn_r and z = x @ Wc + bc computed by
//    dense GEMM first (linearity of mean); fused gather kernel then computes
//    h = relu(z + mean_r0(y0) + mean_r1(y1)) per node -> bf16, no f32 acc
//    round-trip. Layer-2 gather rows are 64-wide (128 B/edge, 6.4 MB tables).
//  * gather = wave-per-node, coalesced full-row reads (round-4 style; the
//    round-5 lane-per-node slicing was L2 request-count bound).
//  * scores written directly (no partials round-trip).
//  * radix CSR build kept; partition re-reads edges (no big reg arrays).
// ---------------------------------------------------------------------------

#define BW 128            // nodes per radix bucket (pow2)
#define NBK_MAX 1024
#define EPB 8192          // edges per block in radix passes

__device__ __forceinline__ unsigned short f2bf(float f) {
    unsigned u = __float_as_uint(f);
    unsigned r = u + 0x7FFFu + ((u >> 16) & 1u);
    return (unsigned short)(r >> 16);
}
__device__ __forceinline__ unsigned pack2(float a, float b) {
    return (unsigned)f2bf(a) | ((unsigned)f2bf(b) << 16);
}
__device__ __forceinline__ float bflo(unsigned v) { return __uint_as_float(v << 16); }
__device__ __forceinline__ float bfhi(unsigned v) { return __uint_as_float(v & 0xFFFF0000u); }

// ---- radix pass A: per-(r,bucket) counts --------------------------------
__global__ __launch_bounds__(256) void
bucket_count_kernel(const int* __restrict__ edges, int* __restrict__ bcnt,
                    int NBK, int E)
{
    __shared__ int cnt[2 * NBK_MAX];
    const int rbT = 2 * NBK;
    const int t = threadIdx.x;
    for (int k = t; k < rbT; k += 256) cnt[k] = 0;
    __syncthreads();
    long long start = (long long)blockIdx.x * EPB;
    long long twoE = 2LL * E;
    for (int u = 0; u < EPB / 256; ++u) {
        long long idx = start + u * 256 + t;
        if (idx < twoE) {
            int r = idx >= E;
            int e = (int)(idx - (long long)r * E);
            int d = edges[(size_t)r * 2 * E + E + e];
            atomicAdd(&cnt[r * NBK + (d >> 7)], 1);
        }
    }
    __syncthreads();
    for (int k = t; k < rbT; k += 256)
        if (cnt[k]) atomicAdd(&bcnt[k], cnt[k]);
}

// ---- radix pass B: exclusive scan of bucket counts (one block) ----------
__global__ __launch_bounds__(1024) void
bucket_scan_kernel(const int* __restrict__ bcnt, int* __restrict__ bko,
                   int rbT, int twoE)
{
    __shared__ int sm[1024];
    int t = threadIdx.x;
    int v = (t < rbT) ? bcnt[t] : 0;
    sm[t] = v;
    __syncthreads();
    for (int s = 1; s < 1024; s <<= 1) {
        int u = (t >= s) ? sm[t - s] : 0;
        __syncthreads();
        sm[t] += u;
        __syncthreads();
    }
    if (t < rbT) bko[t] = sm[t] - v;
    if (t == 0) bko[rbT] = twoE;
}

// ---- radix pass C: partition into bucket-grouped (src,dst) pairs --------
__global__ __launch_bounds__(256) void
partition_kernel(const int* __restrict__ edges, const int* __restrict__ bko,
                 int* __restrict__ gcur, uint2* __restrict__ staging,
                 int NBK, int E)
{
    __shared__ int cnt[2 * NBK_MAX];
    __shared__ int base[2 * NBK_MAX];
    const int rbT = 2 * NBK;
    const int t = threadIdx.x;
    for (int k = t; k < rbT; k += 256) cnt[k] = 0;
    __syncthreads();
    long long start = (long long)blockIdx.x * EPB;
    long long twoE = 2LL * E;
    for (int u = 0; u < EPB / 256; ++u) {
        long long idx = start + u * 256 + t;
        if (idx < twoE) {
            int r = idx >= E;
            int e = (int)(idx - (long long)r * E);
            int d = edges[(size_t)r * 2 * E + E + e];
            atomicAdd(&cnt[r * NBK + (d >> 7)], 1);
        }
    }
    __syncthreads();
    for (int k = t; k < rbT; k += 256) {
        int c0 = cnt[k];
        if (c0) base[k] = bko[k] + atomicAdd(&gcur[k], c0);
        cnt[k] = 0;
    }
    __syncthreads();
    for (int u = 0; u < EPB / 256; ++u) {
        long long idx = start + u * 256 + t;
        if (idx < twoE) {
            int r = idx >= E;
            int e = (int)(idx - (long long)r * E);
            int s = edges[(size_t)r * 2 * E + e];
            int d = edges[(size_t)r * 2 * E + E + e];
            int rb = r * NBK + (d >> 7);
            int pos = atomicAdd(&cnt[rb], 1);
            staging[(size_t)base[rb] + pos] = make_uint2((unsigned)s, (unsigned)d);
        }
    }
}

// ---- radix pass D: per-bucket node hist/scan -> off[] and csr[] ----------
__global__ __launch_bounds__(256) void
bucket_csr_kernel(const uint2* __restrict__ staging, const int* __restrict__ bko,
                  int* __restrict__ csr, int* __restrict__ off,
                  int NBK, int N)
{
    __shared__ int hist[BW], excl[BW], cur[BW], sc[BW];
    const int rb = blockIdx.x;
    const int r = rb / NBK;
    const int b = rb % NBK;
    const int node0 = b * BW;
    const int nn = min(BW, N - node0);
    const int cbase = bko[rb];
    const int c = bko[rb + 1] - cbase;
    const int t = threadIdx.x;

    if (t < BW) { hist[t] = 0; cur[t] = 0; }
    __syncthreads();
    for (int k = t; k < c; k += 256)
        atomicAdd(&hist[(int)staging[(size_t)cbase + k].y - node0], 1);
    __syncthreads();
    if (t < BW) sc[t] = hist[t];
    __syncthreads();
    for (int s = 1; s < BW; s <<= 1) {
        int v = (t < BW && t >= s) ? sc[t - s] : 0;
        __syncthreads();
        if (t < BW) sc[t] += v;
        __syncthreads();
    }
    if (t < BW) excl[t] = sc[t] - hist[t];
    if (t < nn) off[(size_t)r * N + node0 + t] = cbase + excl[t];
    __syncthreads();
    for (int k = t; k < c; k += 256) {
        uint2 pr = staging[(size_t)cbase + k];
        int l = (int)pr.y - node0;
        int pos = atomicAdd(&cur[l], 1);
        csr[(size_t)cbase + excl[l] + pos] = (int)pr.x;
    }
}

// ---- f32 -> bf16 --------------------------------------------------------
__global__ void cvt_kernel(const float* __restrict__ in,
                           unsigned short* __restrict__ o, int n4)
{
    int t = blockIdx.x * blockDim.x + threadIdx.x;
    if (t >= n4) return;
    float4 v = ((const float4*)in)[t];
    ushort4 r;
    r.x = f2bf(v.x); r.y = f2bf(v.y); r.z = f2bf(v.z); r.w = f2bf(v.w);
    ((ushort4*)o)[t] = r;
}

// ---- Wself/bias combine --------------------------------------------------
__global__ void prep_kernel(const float* __restrict__ Ws1, const float* __restrict__ b1,
                            const float* __restrict__ Ws2, const float* __restrict__ b2,
                            float* __restrict__ Wc1, float* __restrict__ bc1,
                            float* __restrict__ Wc2, float* __restrict__ bc2)
{
    int t = blockIdx.x * blockDim.x + threadIdx.x;
    if (t < 16384) Wc1[t] = Ws1[t] + Ws1[16384 + t];
    if (t < 128)   bc1[t] = b1[t] + b1[128 + t];
    if (t < 8192)  Wc2[t] = Ws2[t] + Ws2[8192 + t];
    if (t < 64)    bc2[t] = b2[t] + b2[64 + t];
}

// ---- GEMM: blockIdx.y selects {z=A@Wz+bias (f32), ya=A@Wa, yb=A@Wb (bf16)}
// A bf16 [N,128]; W f32 [128,BN]. 256 thr, 8x4 reg tile.
template<int BN>
__global__ __launch_bounds__(256) void
gemm_kernel(const unsigned short* __restrict__ Ab,
            const float* __restrict__ Wz, const float* __restrict__ Wa,
            const float* __restrict__ Wb, const float* __restrict__ bias,
            float* __restrict__ zf,
            unsigned short* __restrict__ ya, unsigned short* __restrict__ yb,
            int N)
{
    constexpr int TCOLS = BN / 4;
    constexpr int TROWS = 256 / TCOLS;
    constexpr int BM = TROWS * 8;
    constexpr int BK = 32;
    constexpr int F4_PER_WROW = BN / 4;

    __shared__ float As[BK][BM + 4];
    __shared__ float Wsm[BK][BN];

    const int sel = blockIdx.y;
    const float* W = (sel == 0) ? Wz : ((sel == 1) ? Wa : Wb);

    const int tid = threadIdx.x;
    const int tc = tid % TCOLS;
    const int tr = tid / TCOLS;
    const int j0 = tc * 4;
    const int i0 = tr * 8;
    const int rowBase = blockIdx.x * BM;

    float acc[8][4];
#pragma unroll
    for (int r = 0; r < 8; ++r)
#pragma unroll
        for (int c = 0; c < 4; ++c) acc[r][c] = 0.0f;

    for (int k0 = 0; k0 < 128; k0 += BK) {
        constexpr int A_U4 = BM * 4;               // uint4 (8 bf16) per 32-col chunk
#pragma unroll
        for (int p = 0; p < A_U4 / 256; ++p) {
            int q = tid + p * 256;
            int row = q >> 2;
            int part = q & 3;
            int kq = part * 8;
            int rg = rowBase + row;
            if (rg >= N) rg = N - 1;
            uint4 v = *(const uint4*)(Ab + (size_t)rg * 128 + k0 + kq);
            As[kq + 0][row] = bflo(v.x);
            As[kq + 1][row] = bfhi(v.x);
            As[kq + 2][row] = bflo(v.y);
            As[kq + 3][row] = bfhi(v.y);
            As[kq + 4][row] = bflo(v.z);
            As[kq + 5][row] = bfhi(v.z);
            As[kq + 6][row] = bflo(v.w);
            As[kq + 7][row] = bfhi(v.w);
        }
        constexpr int W_F4 = BK * F4_PER_WROW;
#pragma unroll
        for (int p = 0; p < W_F4 / 256; ++p) {
            int q = tid + p * 256;
            int rk = q / F4_PER_WROW;
            int jq = (q % F4_PER_WROW) * 4;
            float4 v = *(const float4*)(W + (size_t)(k0 + rk) * BN + jq);
            *(float4*)&Wsm[rk][jq] = v;
        }
        __syncthreads();

#pragma unroll 8
        for (int k = 0; k < BK; ++k) {
            float4 w = *(const float4*)&Wsm[k][j0];
            const float* ap = &As[k][i0];
            float4 a0 = *(const float4*)(ap);
            float4 a1 = *(const float4*)(ap + 4);
            float av[8] = {a0.x, a0.y, a0.z, a0.w, a1.x, a1.y, a1.z, a1.w};
#pragma unroll
            for (int r = 0; r < 8; ++r) {
                acc[r][0] = fmaf(av[r], w.x, acc[r][0]);
                acc[r][1] = fmaf(av[r], w.y, acc[r][1]);
                acc[r][2] = fmaf(av[r], w.z, acc[r][2]);
                acc[r][3] = fmaf(av[r], w.w, acc[r][3]);
            }
        }
        __syncthreads();
    }

    float4 bv = make_float4(0.f, 0.f, 0.f, 0.f);
    if (sel == 0) bv = *(const float4*)(bias + j0);
    unsigned short* ob = (sel == 1) ? ya : yb;
#pragma unroll
    for (int r = 0; r < 8; ++r) {
        int row = rowBase + i0 + r;
        if (row >= N) break;
        float4 o;
        o.x = acc[r][0] + bv.x;
        o.y = acc[r][1] + bv.y;
        o.z = acc[r][2] + bv.z;
        o.w = acc[r][3] + bv.w;
        if (sel == 0) {
            *(float4*)(zf + (size_t)row * BN + j0) = o;
        } else {
            ushort4 u;
            u.x = f2bf(o.x); u.y = f2bf(o.y); u.z = f2bf(o.z); u.w = f2bf(o.w);
            *(ushort4*)(ob + (size_t)row * BN + j0) = u;
        }
    }
}

// ---- fused aggregate L1: wave per node, 128 cols -------------------------
// h1 = relu(z1 + mean_r0(y0) + mean_r1(y1)) -> bf16
__global__ __launch_bounds__(256) void
agg1_kernel(const unsigned short* __restrict__ y0,
            const unsigned short* __restrict__ y1,
            const float* __restrict__ z1,
            const int* __restrict__ csr, const int* __restrict__ off,
            unsigned short* __restrict__ h1b, int N, int twoE)
{
    int w = blockIdx.x * 4 + (threadIdx.x >> 6);
    int lane = threadIdx.x & 63;
    if (w >= N) return;
    const int col = lane * 2;

    float sx0 = 0.f, sy0 = 0.f, sx1 = 0.f, sy1 = 0.f;
    int o0 = off[w], o1 = off[w + 1];
    int d0 = o1 - o0;
    int j = o0;
    for (; j + 3 < o1; j += 4) {
        int s0 = csr[j], s1 = csr[j + 1], s2 = csr[j + 2], s3 = csr[j + 3];
        unsigned a = *(const unsigned*)(y0 + (size_t)s0 * 128 + col);
        unsigned b = *(const unsigned*)(y0 + (size_t)s1 * 128 + col);
        unsigned c = *(const unsigned*)(y0 + (size_t)s2 * 128 + col);
        unsigned d = *(const unsigned*)(y0 + (size_t)s3 * 128 + col);
        sx0 += (bflo(a) + bflo(b)) + (bflo(c) + bflo(d));
        sy0 += (bfhi(a) + bfhi(b)) + (bfhi(c) + bfhi(d));
    }
    for (; j < o1; ++j) {
        unsigned a = *(const unsigned*)(y0 + (size_t)csr[j] * 128 + col);
        sx0 += bflo(a); sy0 += bfhi(a);
    }
    int p = N + w;
    o0 = off[p];
    o1 = (p + 1 < 2 * N) ? off[p + 1] : twoE;
    int d1 = o1 - o0;
    j = o0;
    for (; j + 3 < o1; j += 4) {
        int s0 = csr[j], s1 = csr[j + 1], s2 = csr[j + 2], s3 = csr[j + 3];
        unsigned a = *(const unsigned*)(y1 + (size_t)s0 * 128 + col);
        unsigned b = *(const unsigned*)(y1 + (size_t)s1 * 128 + col);
        unsigned c = *(const unsigned*)(y1 + (size_t)s2 * 128 + col);
        unsigned d = *(const unsigned*)(y1 + (size_t)s3 * 128 + col);
        sx1 += (bflo(a) + bflo(b)) + (bflo(c) + bflo(d));
        sy1 += (bfhi(a) + bfhi(b)) + (bfhi(c) + bfhi(d));
    }
    for (; j < o1; ++j) {
        unsigned a = *(const unsigned*)(y1 + (size_t)csr[j] * 128 + col);
        sx1 += bflo(a); sy1 += bfhi(a);
    }
    float inv0 = 1.0f / fmaxf((float)d0, 1.0f);
    float inv1 = 1.0f / fmaxf((float)d1, 1.0f);
    float2 z = *(const float2*)(z1 + (size_t)w * 128 + col);
    float hx = fmaxf(z.x + sx0 * inv0 + sx1 * inv1, 0.0f);
    float hy = fmaxf(z.y + sy0 * inv0 + sy1 * inv1, 0.0f);
    *(unsigned*)(h1b + (size_t)w * 128 + col) = pack2(hx, hy);
}

// ---- fused aggregate L2: wave per node, 64 cols, 2 edges/iter ------------
// h2 = z2 + mean_r0(t0) + mean_r1(t1) -> bf16 (no relu)
__global__ __launch_bounds__(256) void
agg2_kernel(const unsigned short* __restrict__ t0,
            const unsigned short* __restrict__ t1,
            const float* __restrict__ z2,
            const int* __restrict__ csr, const int* __restrict__ off,
            unsigned short* __restrict__ h2b, int N, int twoE)
{
    int w = blockIdx.x * 4 + (threadIdx.x >> 6);
    int lane = threadIdx.x & 63;
    if (w >= N) return;
    const int half = lane >> 5;
    const int col = (lane & 31) * 2;

    float sx0 = 0.f, sy0 = 0.f, sx1 = 0.f, sy1 = 0.f;
    int o0 = off[w], o1 = off[w + 1];
    int d0 = o1 - o0;
    for (int j = o0 + half; j < o1; j += 2) {
        unsigned a = *(const unsigned*)(t0 + (size_t)csr[j] * 64 + col);
        sx0 += bflo(a); sy0 += bfhi(a);
    }
    int p = N + w;
    o0 = off[p];
    o1 = (p + 1 < 2 * N) ? off[p + 1] : twoE;
    int d1 = o1 - o0;
    for (int j = o0 + half; j < o1; j += 2) {
        unsigned a = *(const unsigned*)(t1 + (size_t)csr[j] * 64 + col);
        sx1 += bflo(a); sy1 += bfhi(a);
    }
    sx0 += __shfl_xor(sx0, 32);
    sy0 += __shfl_xor(sy0, 32);
    sx1 += __shfl_xor(sx1, 32);
    sy1 += __shfl_xor(sy1, 32);
    if (half == 0) {
        float inv0 = 1.0f / fmaxf((float)d0, 1.0f);
        float inv1 = 1.0f / fmaxf((float)d1, 1.0f);
        float2 z = *(const float2*)(z2 + (size_t)w * 64 + col);
        float hx = z.x + sx0 * inv0 + sx1 * inv1;
        float hy = z.y + sy0 * inv0 + sy1 * inv1;
        *(unsigned*)(h2b + (size_t)w * 64 + col) = pack2(hx, hy);
    }
}

// ---- score: 8 lanes/edge, coalesced 128B rows, shfl reduce ---------------
__global__ __launch_bounds__(256) void
score_kernel(const unsigned short* __restrict__ h, // [N,64] bf16
             const int* __restrict__ src, const int* __restrict__ dst,
             float* __restrict__ out, int E)
{
    int t = blockIdx.x * blockDim.x + threadIdx.x;
    int e = t >> 3;
    int c = t & 7;
    if (e >= E) return;
    uint4 va = *(const uint4*)(h + (size_t)src[e] * 64 + c * 8);
    uint4 vb = *(const uint4*)(h + (size_t)dst[e] * 64 + c * 8);
    float s = 0.0f;
    s = fmaf(bflo(va.x), bflo(vb.x), s);
    s = fmaf(bfhi(va.x), bfhi(vb.x), s);
    s = fmaf(bflo(va.y), bflo(vb.y), s);
    s = fmaf(bfhi(va.y), bfhi(vb.y), s);
    s = fmaf(bflo(va.z), bflo(vb.z), s);
    s = fmaf(bfhi(va.z), bfhi(vb.z), s);
    s = fmaf(bflo(va.w), bflo(vb.w), s);
    s = fmaf(bfhi(va.w), bfhi(vb.w), s);
    s += __shfl_xor(s, 1);
    s += __shfl_xor(s, 2);
    s += __shfl_xor(s, 4);
    if (c == 0) out[e] = s;
}

extern "C" void kernel_launch(void* const* d_in, const int* in_sizes, int n_in,
                              void* d_out, int out_size, void* d_ws, size_t ws_size,
                              hipStream_t stream)
{
    const float* x     = (const float*)d_in[0];
    const int*   edges = (const int*)d_in[1];
    const int*   neg   = (const int*)d_in[2];
    const float* Wn1   = (const float*)d_in[3];
    const float* Ws1   = (const float*)d_in[4];
    const float* b1    = (const float*)d_in[5];
    const float* Wn2   = (const float*)d_in[6];
    const float* Ws2   = (const float*)d_in[7];
    const float* b2    = (const float*)d_in[8];
    float* out = (float*)d_out;

    const int Fin = 128, R = 2;
    const int N  = in_sizes[0] / Fin;        // 50000
    const int E  = in_sizes[1] / (R * 2);    // 800000
    const int En = in_sizes[2] / 2;          // 800000
    const int twoE = 2 * E;
    const int NBK = (N + BW - 1) / BW;       // 391
    const int rbT = 2 * NBK;

    // ---- workspace layout (aliases noted) ----
    float* ws = (float*)d_ws;
    float* z1 = ws;                                    // [N,128] f32 25.6MB (also staging alias; z2 reuses)
    unsigned short* y0  = (unsigned short*)(z1 + (size_t)N * 128);  // [N,128] bf16 (t0 reuses)
    unsigned short* y1  = y0 + (size_t)N * 128;        // [N,128] bf16 (t1 reuses first half, h2b second half)
    unsigned short* xb  = y1 + (size_t)N * 128;        // [N,128] bf16
    unsigned short* h1b = xb + (size_t)N * 128;        // [N,128] bf16
    float* Wc1 = (float*)(h1b + (size_t)N * 128);      // [128,128]
    float* bc1 = Wc1 + 16384;
    float* Wc2 = bc1 + 128;                            // [128,64]
    float* bc2 = Wc2 + 8192;
    int* bcnt = (int*)(bc2 + 64);                      // [2*NBK_MAX]
    int* gcur = bcnt + 2 * NBK_MAX;                    // [2*NBK_MAX]
    int* bko  = gcur + 2 * NBK_MAX;                    // [2*NBK_MAX+1]
    int* off  = bko + 2 * NBK_MAX + 1;                 // [2N]
    int* csr  = off + (size_t)2 * N;                   // [2E]

    uint2* staging = (uint2*)z1;                       // [2E] pairs, dead before gemm1
    float* z2 = z1;                                    // [N,64] f32, reuses z1 region
    unsigned short* t0 = y0;                           // [N,64] bf16
    unsigned short* t1 = y1;                           // [N,64] bf16
    unsigned short* h2b = y1 + (size_t)N * 64;         // [N,64] bf16, tail of y1 region

    const int BS = 256;
    const int edge_blocks = (twoE + EPB - 1) / EPB;

    // ---- CSR build (radix by dst bucket) ----
    hipMemsetAsync(bcnt, 0, (size_t)4 * NBK_MAX * sizeof(int), stream);
    bucket_count_kernel<<<edge_blocks, BS, 0, stream>>>(edges, bcnt, NBK, E);
    bucket_scan_kernel<<<1, 1024, 0, stream>>>(bcnt, bko, rbT, twoE);
    partition_kernel<<<edge_blocks, BS, 0, stream>>>(edges, bko, gcur, staging, NBK, E);
    bucket_csr_kernel<<<rbT, BS, 0, stream>>>(staging, bko, csr, off, NBK, N);

    // ---- prep ----
    cvt_kernel<<<(N * 32 + BS - 1) / BS, BS, 0, stream>>>(x, xb, N * 32);
    prep_kernel<<<(16384 + BS - 1) / BS, BS, 0, stream>>>(Ws1, b1, Ws2, b2, Wc1, bc1, Wc2, bc2);

    // ---- Layer 1: transform then aggregate ----
    {
        dim3 g((N + 63) / 64, 3);
        gemm_kernel<128><<<g, BS, 0, stream>>>(xb, Wc1, Wn1, Wn1 + 16384, bc1,
                                               z1, y0, y1, N);
    }
    agg1_kernel<<<(N + 3) / 4, BS, 0, stream>>>(y0, y1, z1, csr, off, h1b, N, twoE);

    // ---- Layer 2 ----
    {
        dim3 g((N + 127) / 128, 3);
        gemm_kernel<64><<<g, BS, 0, stream>>>(h1b, Wc2, Wn2, Wn2 + 8192, bc2,
                                              z2, t0, t1, N);
    }
    agg2_kernel<<<(N + 3) / 4, BS, 0, stream>>>(t0, t1, z2, csr, off, h2b, N, twoE);

    // ---- Scores ----
    score_kernel<<<(E * 8 + BS - 1) / BS, BS, 0, stream>>>(h2b, edges, edges + E, out, E);
    score_kernel<<<(En * 8 + BS - 1) / BS, BS, 0, stream>>>(h2b, neg, neg + En, out + E, En);
}